// Round 1
// baseline (191.579 us; speedup 1.0000x reference)
//
#include <hip/hip_runtime.h>
#include <math.h>

#define B_  128
#define C_  3
#define L_  2048
#define K_  128
#define S_  50
#define W_  (L_ - S_ + 1)          /* 1999 */
#define TW  64
#define NT  ((W_ + TW - 1) / TW)   /* 32 tiles */

__global__ void init_out_kernel(float* out) {
    int i = blockIdx.x * blockDim.x + threadIdx.x;
    if (i < B_ * K_) out[i] = __int_as_float(0x7F800000); // +inf
}

__global__ __launch_bounds__(256) void shapelet_min_kernel(
        const float* __restrict__ x, const float* __restrict__ sh,
        float* __restrict__ out) {
    const int b    = blockIdx.x / NT;
    const int tile = blockIdx.x % NT;
    const int w0   = tile * TW;
    const int t    = threadIdx.x;
    const int k    = t & (K_ - 1);
    const int half = t >> 7;            // 0 or 1: which 32-w half this thread owns

    __shared__ float xs[TW + S_ - 1];   // 113 floats, one channel at a time
    __shared__ float sqw[TW];           // ||window||^2 per w
    __shared__ float dsum[TW][K_];      // 32 KB: sum over c of dist, per (w,k)
    __shared__ float mins[2][K_];

    // zero my dsum entries
    #pragma unroll
    for (int g = 0; g < 4; ++g) {
        int wb = half * 32 + g * 8;
        #pragma unroll
        for (int j = 0; j < 8; ++j) dsum[wb + j][k] = 0.f;
    }

    for (int c = 0; c < C_; ++c) {
        __syncthreads();   // prior-iteration readers of xs/sqw done
        if (t < TW + S_ - 1) {
            int idx = w0 + t;
            xs[t] = (idx < L_) ? x[(b * C_ + c) * L_ + idx] : 0.f;
        }
        __syncthreads();
        if (t < TW) {
            float a = 0.f;
            #pragma unroll
            for (int s = 0; s < S_; ++s) { float v = xs[t + s]; a += v * v; }
            sqw[t] = a;
        }
        // shapelet row for my k, plus its squared norm (registers)
        float shreg[S_];
        float sqs = 0.f;
        const float* __restrict__ shp = sh + (c * K_ + k) * S_;
        #pragma unroll
        for (int s = 0; s < S_; ++s) { shreg[s] = shp[s]; sqs += shreg[s] * shreg[s]; }
        __syncthreads();

        // 4 groups of 8 w's, rolling 8-register x window: 8 FMA per ds_read
        #pragma unroll
        for (int g = 0; g < 4; ++g) {
            int wb = half * 32 + g * 8;
            float dot[8];
            #pragma unroll
            for (int j = 0; j < 8; ++j) dot[j] = 0.f;
            float xw[8];
            #pragma unroll
            for (int j = 0; j < 7; ++j) xw[j] = xs[wb + j];
            #pragma unroll
            for (int s = 0; s < S_; ++s) {
                xw[(s + 7) & 7] = xs[wb + s + 7];
                #pragma unroll
                for (int j = 0; j < 8; ++j) dot[j] += shreg[s] * xw[(s + j) & 7];
            }
            #pragma unroll
            for (int j = 0; j < 8; ++j) {
                float d2 = sqw[wb + j] + sqs - 2.f * dot[j];
                dsum[wb + j][k] += sqrtf(fmaxf(d2, 0.f));
            }
        }
    }
    __syncthreads();

    // min over my 32 w's (only valid w)
    float m = __int_as_float(0x7F800000);
    #pragma unroll
    for (int g = 0; g < 4; ++g) {
        int wb = half * 32 + g * 8;
        #pragma unroll
        for (int j = 0; j < 8; ++j) {
            int wg = w0 + wb + j;
            if (wg < W_) m = fminf(m, dsum[wb + j][k]);
        }
    }
    mins[half][k] = m;
    __syncthreads();
    if (half == 0) {
        float v = fminf(mins[0][k], mins[1][k]);
        // all values >= 0 -> int compare on float bits is order-preserving
        atomicMin(reinterpret_cast<int*>(out) + b * K_ + k, __float_as_int(v));
    }
}

extern "C" void kernel_launch(void* const* d_in, const int* in_sizes, int n_in,
                              void* d_out, int out_size, void* d_ws, size_t ws_size,
                              hipStream_t stream) {
    const float* x  = (const float*)d_in[0];   // (128,3,2048) f32
    const float* sh = (const float*)d_in[1];   // (3,128,50)  f32
    float* out = (float*)d_out;                // (128,1,128) f32

    init_out_kernel<<<(B_ * K_ + 255) / 256, 256, 0, stream>>>(out);
    shapelet_min_kernel<<<B_ * NT, 256, 0, stream>>>(x, sh, out);
}

// Round 2
// 87.009 us; speedup vs baseline: 2.2018x; 2.2018x over previous
//
#include <hip/hip_runtime.h>
#include <math.h>

#define B_  128
#define C_  3
#define L_  2048
#define K_  128
#define S_  50
#define W_  (L_ - S_ + 1)          /* 1999 */
#define TW  64
#define NT  ((W_ + TW - 1) / TW)   /* 32 tiles (exactly 32, power of 2) */

typedef __attribute__((ext_vector_type(8))) short bf16x8;
typedef __attribute__((ext_vector_type(4))) float f32x4;

__device__ __forceinline__ unsigned short f2bf(float f) {
    unsigned int u = __float_as_uint(f);
    u += 0x7FFFu + ((u >> 16) & 1u);   // RNE (inputs finite)
    return (unsigned short)(u >> 16);
}

// ws layout:
//   sqw  : float[B_*C_*2048]                  offset 0        (3,145,728 B)
//   frag : uint4[C_*2*8*64]                   offset 3145728  (49,152 B)
//   sqs  : float[C_*K_]                       offset 3194880  (1,536 B)
#define WS_SQW_OFF  0
#define WS_FRAG_OFF 3145728
#define WS_SQS_OFF  3194880

// ||window||^2 per (b,c,w); +inf for padding w>=W_ so invalid rows self-mask.
__global__ __launch_bounds__(256) void sqw_kernel(const float* __restrict__ x,
                                                  float* __restrict__ ws_sqw) {
    int i  = blockIdx.x * 256 + threadIdx.x;   // 786432 total
    int w  = i & (L_ - 1);
    int bc = i >> 11;
    float r = __int_as_float(0x7F800000);      // +inf
    if (w < W_) {
        const float* p = x + bc * L_ + w;
        float a = 0.f;
        #pragma unroll 10
        for (int s = 0; s < S_; ++s) { float v = p[s]; a += v * v; }
        r = a;
    }
    ws_sqw[i] = r;
}

// Pack shapelets (scaled by -2) into MFMA B-fragment order, compute ||s||^2,
// and init out to +inf.
__global__ __launch_bounds__(256) void prep_kernel(const float* __restrict__ sh,
                                                   uint4* __restrict__ ws_frag,
                                                   float* __restrict__ ws_sqs,
                                                   float* __restrict__ out) {
    int t = blockIdx.x * 256 + threadIdx.x;
    if (t < 3072) {
        // t = ((c*2 + ks)*8 + nq)*64 + l
        int c  = t >> 10;
        int rem = t & 1023;
        int ks = rem >> 9;
        int nq = (rem >> 6) & 7;
        int l  = rem & 63;
        int k  = nq * 16 + (l & 15);           // B col = lane&15
        int s0 = ks * 32 + (l >> 4) * 8;       // B k   = 8*(lane>>4)+j
        const float* sp = sh + (c * K_ + k) * S_;
        unsigned short h[8];
        #pragma unroll
        for (int j = 0; j < 8; ++j) {
            int s = s0 + j;
            float v = (s < S_) ? -2.f * sp[s] : 0.f;
            h[j] = f2bf(v);
        }
        uint4 u;
        u.x = (unsigned)h[0] | ((unsigned)h[1] << 16);
        u.y = (unsigned)h[2] | ((unsigned)h[3] << 16);
        u.z = (unsigned)h[4] | ((unsigned)h[5] << 16);
        u.w = (unsigned)h[6] | ((unsigned)h[7] << 16);
        ws_frag[t] = u;
    } else if (t < 3456) {
        int i = t - 3072;
        int c = i >> 7, k = i & 127;
        const float* sp = sh + (c * K_ + k) * S_;
        float a = 0.f;
        #pragma unroll 10
        for (int s = 0; s < S_; ++s) { float v = sp[s]; a += v * v; }
        ws_sqs[c * K_ + k] = a;
    } else if (t < 3456 + B_ * K_) {
        out[t - 3456] = __int_as_float(0x7F800000);
    }
}

__global__ __launch_bounds__(256) void mfma_main(const float* __restrict__ x,
                                                 const float* __restrict__ ws_sqw,
                                                 const uint4* __restrict__ ws_frag,
                                                 const float* __restrict__ ws_sqs,
                                                 float* __restrict__ out) {
    const int b    = blockIdx.x >> 5;          // / NT
    const int tile = blockIdx.x & (NT - 1);
    const int w0   = tile * TW;
    const int t    = threadIdx.x;
    const int wid  = t >> 6;                   // wave id: owns rows w0+wid*16 .. +15
    const int l    = t & 63;
    const int row  = l & 15;                   // A row / D col
    const int kg   = l >> 4;

    f32x4 dsum[8];
    #pragma unroll
    for (int nq = 0; nq < 8; ++nq) dsum[nq] = (f32x4){0.f, 0.f, 0.f, 0.f};

    #pragma unroll
    for (int c = 0; c < C_; ++c) {
        const float* xrow = x + (b * C_ + c) * L_;
        // A fragments: lane holds A[row][8*kg + j] ; element = x[w0+wid*16+row + s]
        bf16x8 A[2];
        const int eb0 = w0 + wid * 16 + row + kg * 8;
        #pragma unroll
        for (int ks = 0; ks < 2; ++ks) {
            const int eb = eb0 + ks * 32;
            bf16x8 a;
            #pragma unroll
            for (int j = 0; j < 8; ++j) {
                int e = eb + j;
                float v = (e < L_) ? xrow[e] : 0.f;
                a[j] = (short)f2bf(v);
            }
            A[ks] = a;
        }
        // ||window||^2 for this lane's 4 D-rows (consecutive, 16B-aligned)
        const f32x4 sw = *reinterpret_cast<const f32x4*>(
            ws_sqw + (b * C_ + c) * L_ + w0 + wid * 16 + kg * 4);
        const float* sqs_c = ws_sqs + c * K_;
        const uint4* fragc = ws_frag + c * 2 * 8 * 64;

        #pragma unroll
        for (int nq = 0; nq < 8; ++nq) {
            uint4 b0 = fragc[(0 * 8 + nq) * 64 + l];
            uint4 b1 = fragc[(1 * 8 + nq) * 64 + l];
            f32x4 acc = (f32x4){0.f, 0.f, 0.f, 0.f};
            acc = __builtin_amdgcn_mfma_f32_16x16x32_bf16(
                      A[0], __builtin_bit_cast(bf16x8, b0), acc, 0, 0, 0);
            acc = __builtin_amdgcn_mfma_f32_16x16x32_bf16(
                      A[1], __builtin_bit_cast(bf16x8, b1), acc, 0, 0, 0);
            float ss = sqs_c[nq * 16 + row];
            #pragma unroll
            for (int r = 0; r < 4; ++r) {
                float d2 = sw[r] + ss + acc[r];   // acc = -2*dot
                d2 = fmaxf(d2, 0.f);
                dsum[nq][r] += sqrtf(d2);
            }
        }
    }

    // min over this wave's 16 rows, then across waves, then global atomicMin
    __shared__ float bmin[4][K_];
    #pragma unroll
    for (int nq = 0; nq < 8; ++nq) {
        float m = fminf(fminf(dsum[nq][0], dsum[nq][1]),
                        fminf(dsum[nq][2], dsum[nq][3]));
        m = fminf(m, __shfl_xor(m, 16));
        m = fminf(m, __shfl_xor(m, 32));
        if (kg == 0) bmin[wid][nq * 16 + row] = m;
    }
    __syncthreads();
    if (t < K_) {
        float v = fminf(fminf(bmin[0][t], bmin[1][t]),
                        fminf(bmin[2][t], bmin[3][t]));
        atomicMin(reinterpret_cast<int*>(out) + b * K_ + t, __float_as_int(v));
    }
}

extern "C" void kernel_launch(void* const* d_in, const int* in_sizes, int n_in,
                              void* d_out, int out_size, void* d_ws, size_t ws_size,
                              hipStream_t stream) {
    const float* x  = (const float*)d_in[0];   // (128,3,2048) f32
    const float* sh = (const float*)d_in[1];   // (3,128,50)  f32
    float* out = (float*)d_out;                // (128,1,128) f32

    float* ws_sqw  = (float*)((char*)d_ws + WS_SQW_OFF);
    uint4* ws_frag = (uint4*)((char*)d_ws + WS_FRAG_OFF);
    float* ws_sqs  = (float*)((char*)d_ws + WS_SQS_OFF);

    sqw_kernel<<<(B_ * C_ * L_) / 256, 256, 0, stream>>>(x, ws_sqw);
    prep_kernel<<<(3456 + B_ * K_ + 255) / 256, 256, 0, stream>>>(sh, ws_frag, ws_sqs, out);
    mfma_main<<<B_ * NT, 256, 0, stream>>>(x, ws_sqw, ws_frag, ws_sqs, out);
}

// Round 4
// 54.769 us; speedup vs baseline: 3.4979x; 1.5886x over previous
//
#include <hip/hip_runtime.h>
#include <math.h>

#define B_  128
#define C_  3
#define L_  2048
#define K_  128
#define S_  50
#define W_  (L_ - S_ + 1)          /* 1999 */
#define TW  64
#define NT  32
#define XPAD 2112                  /* padded bf16 row length (covers max read 2110) */
#define BIGW 1e30f

typedef __attribute__((ext_vector_type(8))) short bf16x8;
typedef __attribute__((ext_vector_type(4))) float f32x4;
typedef uint4 uint4_a4 __attribute__((aligned(4)));   /* 16B load at 4B alignment */

__device__ __forceinline__ unsigned short f2bf(float f) {
    unsigned int u = __float_as_uint(f);
    u += 0x7FFFu + ((u >> 16) & 1u);   // RNE (inputs finite)
    return (unsigned short)(u >> 16);
}
__device__ __forceinline__ float bf2f(unsigned short h) {
    return __uint_as_float(((unsigned int)h) << 16);
}

// ws layout (bytes):
//   sqw : float[B_*C_*L_]            @ 0         (3,145,728)
//   xb0 : bf16 [B_*C_*XPAD]          @ 3145728   (1,622,016)
//   xb1 : bf16 [B_*C_*XPAD] (shift1) @ 4767744   (1,622,016)
//   frag: uint4[C_*2*8*64]           @ 6389760   (49,152)  -> total 6,438,912
#define WS_SQW_OFF  0
#define WS_XB0_OFF  3145728
#define WS_XB1_OFF  4767744
#define WS_FRAG_OFF 6389760

// ||window||^2 per (b,c,w); large-finite for padding w>=W_ (self-masking, no inf/NaN).
__global__ __launch_bounds__(256) void sqw_kernel(const float* __restrict__ x,
                                                  float* __restrict__ ws_sqw) {
    int i  = blockIdx.x * 256 + threadIdx.x;   // 786432 total
    int w  = i & (L_ - 1);
    int bc = i >> 11;
    float r = BIGW;
    if (w < W_) {
        const float* p = x + bc * L_ + w;
        float a = 0.f;
        #pragma unroll 10
        for (int s = 0; s < S_; ++s) { float v = p[s]; a += v * v; }
        r = a;
    }
    ws_sqw[i] = r;
}

// x -> bf16, two parity copies (xb1 shifted by one element), zero tail pad.
__global__ __launch_bounds__(256) void cvt_kernel(const float* __restrict__ x,
                                                  unsigned int* __restrict__ xb0,
                                                  unsigned int* __restrict__ xb1) {
    int i   = blockIdx.x * 256 + threadIdx.x;  // word index, B_*C_*XPAD/2 = 405504
    int row = i / (XPAD / 2);
    int pos = (i - row * (XPAD / 2)) * 2;
    const float* xr = x + row * L_;
    float v0 = (pos     < L_) ? xr[pos]     : 0.f;
    float v1 = (pos + 1 < L_) ? xr[pos + 1] : 0.f;
    float v2 = (pos + 2 < L_) ? xr[pos + 2] : 0.f;
    xb0[i] = (unsigned)f2bf(v0) | ((unsigned)f2bf(v1) << 16);
    xb1[i] = (unsigned)f2bf(v1) | ((unsigned)f2bf(v2) << 16);
}

// Shapelet B-fragments in MFMA order, -2x scaled; K-pad slots carry the norms:
//   s=50: bf16_hi(||s||^2)  s=51: bf16_lo residual  s=52,53: 1.0  s>=54: 0
// Also init out to +inf.
__global__ __launch_bounds__(256) void prep_kernel(const float* __restrict__ sh,
                                                   uint4* __restrict__ ws_frag,
                                                   float* __restrict__ out) {
    int t = blockIdx.x * 256 + threadIdx.x;
    if (t < 3072) {
        int c  = t >> 10;
        int rem = t & 1023;
        int ks = rem >> 9;
        int nq = (rem >> 6) & 7;
        int l  = rem & 63;
        int k  = nq * 16 + (l & 15);
        int s0 = ks * 32 + (l >> 4) * 8;
        const float* sp = sh + (c * K_ + k) * S_;
        float ss = 0.f;
        #pragma unroll 10
        for (int s = 0; s < S_; ++s) { float v = sp[s]; ss += v * v; }
        unsigned short ss_hi = f2bf(ss);
        unsigned short ss_lo = f2bf(ss - bf2f(ss_hi));
        unsigned short h[8];
        #pragma unroll
        for (int j = 0; j < 8; ++j) {
            int s = s0 + j;
            unsigned short v;
            if      (s < S_)             v = f2bf(-2.f * sp[s]);
            else if (s == 50)            v = ss_hi;
            else if (s == 51)            v = ss_lo;
            else if (s == 52 || s == 53) v = 0x3F80;   // 1.0 bf16
            else                         v = 0;
            h[j] = v;
        }
        uint4 u;
        u.x = (unsigned)h[0] | ((unsigned)h[1] << 16);
        u.y = (unsigned)h[2] | ((unsigned)h[3] << 16);
        u.z = (unsigned)h[4] | ((unsigned)h[5] << 16);
        u.w = (unsigned)h[6] | ((unsigned)h[7] << 16);
        ws_frag[t] = u;
    } else if (t >= 4096 && t < 4096 + B_ * K_) {
        out[t - 4096] = __int_as_float(0x7F800000); // +inf
    }
}

__global__ __launch_bounds__(256) void mfma_main(const float* __restrict__ ws_sqw,
                                                 const char* __restrict__ xb0,
                                                 const char* __restrict__ xb1,
                                                 const uint4* __restrict__ ws_frag,
                                                 float* __restrict__ out) {
    const int b    = blockIdx.x >> 5;
    const int tile = blockIdx.x & (NT - 1);
    const int w0   = tile * TW;
    const int t    = threadIdx.x;
    const int wid  = t >> 6;
    const int l    = t & 63;
    const int row  = l & 15;
    const int kg   = l >> 4;
    const int wrow = w0 + wid * 16 + row;      // this lane's A-row (window index)
    const int eb0  = wrow + kg * 8;            // first A element (x index), +32 for ks=1

    // parity-aligned bf16 base: both cases give a 4B-aligned address for x[eb0..]
    const char* xbase = (row & 1) ? (xb1 + 2 * (eb0 - 1)) : (xb0 + 2 * eb0);
    const float* sqwp = ws_sqw + b * C_ * L_ + wrow;

    f32x4 dsum[8];
    #pragma unroll
    for (int nq = 0; nq < 8; ++nq) dsum[nq] = (f32x4){0.f, 0.f, 0.f, 0.f};

    #pragma unroll
    for (int c = 0; c < C_; ++c) {
        const char* xp = xbase + (b * C_ + c) * (XPAD * 2);
        uint4 a0 = *(const uint4_a4*)(xp);
        uint4 a1 = *(const uint4_a4*)(xp + 64);
        // patch ks=1 fragment for kg==2 lanes: s=50,51 -> 1.0,1.0 ; s=52,53 -> sw hi/lo
        float swv = sqwp[c * L_];
        unsigned short hi = f2bf(swv);
        unsigned short lo = f2bf(swv - bf2f(hi));
        unsigned int wz = (unsigned)hi | ((unsigned)lo << 16);
        if (kg == 2) { a1.y = 0x3F803F80u; a1.z = wz; }

        const uint4* fragc = ws_frag + c * 1024;
        #pragma unroll
        for (int nq = 0; nq < 8; ++nq) {
            uint4 b0 = fragc[nq * 64 + l];
            uint4 b1 = fragc[512 + nq * 64 + l];
            f32x4 acc = (f32x4){0.f, 0.f, 0.f, 0.f};
            acc = __builtin_amdgcn_mfma_f32_16x16x32_bf16(
                      __builtin_bit_cast(bf16x8, a0), __builtin_bit_cast(bf16x8, b0), acc, 0, 0, 0);
            acc = __builtin_amdgcn_mfma_f32_16x16x32_bf16(
                      __builtin_bit_cast(bf16x8, a1), __builtin_bit_cast(bf16x8, b1), acc, 0, 0, 0);
            // acc = ||w||^2 + ||s||^2 - 2*dot  (norms folded into the MFMA)
            #pragma unroll
            for (int r = 0; r < 4; ++r)
                dsum[nq][r] += __builtin_amdgcn_sqrtf(fmaxf(acc[r], 0.f));
        }
    }

    __shared__ float bmin[4][K_];
    #pragma unroll
    for (int nq = 0; nq < 8; ++nq) {
        float m = fminf(fminf(dsum[nq][0], dsum[nq][1]),
                        fminf(dsum[nq][2], dsum[nq][3]));
        m = fminf(m, __shfl_xor(m, 16));
        m = fminf(m, __shfl_xor(m, 32));
        if (kg == 0) bmin[wid][nq * 16 + row] = m;
    }
    __syncthreads();
    if (t < K_) {
        float v = fminf(fminf(bmin[0][t], bmin[1][t]),
                        fminf(bmin[2][t], bmin[3][t]));
        atomicMin(reinterpret_cast<int*>(out) + b * K_ + t, __float_as_int(v));
    }
}

extern "C" void kernel_launch(void* const* d_in, const int* in_sizes, int n_in,
                              void* d_out, int out_size, void* d_ws, size_t ws_size,
                              hipStream_t stream) {
    const float* x  = (const float*)d_in[0];   // (128,3,2048) f32
    const float* sh = (const float*)d_in[1];   // (3,128,50)  f32
    float* out = (float*)d_out;                // (128,1,128) f32

    float*        ws_sqw  = (float*)((char*)d_ws + WS_SQW_OFF);
    unsigned int* ws_xb0  = (unsigned int*)((char*)d_ws + WS_XB0_OFF);
    unsigned int* ws_xb1  = (unsigned int*)((char*)d_ws + WS_XB1_OFF);
    uint4*        ws_frag = (uint4*)((char*)d_ws + WS_FRAG_OFF);

    sqw_kernel<<<(B_ * C_ * L_) / 256, 256, 0, stream>>>(x, ws_sqw);
    cvt_kernel<<<(B_ * C_ * XPAD / 2) / 256, 256, 0, stream>>>(x, ws_xb0, ws_xb1);
    prep_kernel<<<(4096 + B_ * K_) / 256, 256, 0, stream>>>(sh, ws_frag, out);
    mfma_main<<<B_ * NT, 256, 0, stream>>>(
        ws_sqw, (const char*)ws_xb0, (const char*)ws_xb1, ws_frag, out);
}